// Round 4
// baseline (3754.939 us; speedup 1.0000x reference)
//
#include <hip/hip_runtime.h>

#define NT 24264
#define NDRUG 20000
#define NGENE 4264
#define NE 100000
#define NREL 5
#define IND 1613
#define D1 1340
#define D2 920
#define D3 740
// padded leading dims (multiples of 8 -> 16B-aligned bf16 rows)
#define PIN 1616
#define PD1 1344
#define PD2 928

typedef unsigned short u16;
typedef unsigned int u32;
typedef short bf16x8 __attribute__((ext_vector_type(8)));
typedef float f32x4 __attribute__((ext_vector_type(4)));

__device__ __forceinline__ u16 f2bf(float f) {
  u32 u = __builtin_bit_cast(u32, f);
  u32 r = (u + 0x7FFFu + ((u >> 16) & 1u)) >> 16;  // RNE
  return (u16)r;
}
__device__ __forceinline__ float bf2f(u16 h) {
  u32 u = ((u32)h) << 16;
  return __builtin_bit_cast(float, u);
}
__device__ __forceinline__ int iclamp(int v, int lo, int hi) {
  return v < lo ? lo : (v > hi ? hi : v);
}

// ---------------- zero int buffer ----------------
__global__ __launch_bounds__(256) void zero_i32_k(int* __restrict__ p, int n) {
  int i = blockIdx.x * 256 + threadIdx.x;
  if (i < n) p[i] = 0;
}

// ---------------- transpose f32 [K][N] -> bf16 [N][ldo], batched ----------------
__global__ __launch_bounds__(256) void transpose_k(
    const float* __restrict__ in, u16* __restrict__ out,
    int K, int N, int ldo, size_t in_batch, size_t out_batch)
{
  __shared__ u16 tile[32][33];
  const int b = blockIdx.z;
  in  += (size_t)b * in_batch;
  out += (size_t)b * out_batch;
  const int n0 = blockIdx.x * 32, k0 = blockIdx.y * 32;
  const int tx = threadIdx.x, ty = threadIdx.y;
  for (int i = ty; i < 32; i += 8) {
    int k = k0 + i, n = n0 + tx;
    tile[i][tx] = (k < K && n < N) ? f2bf(in[(size_t)k * N + n]) : (u16)0;
  }
  __syncthreads();
  for (int i = ty; i < 32; i += 8) {
    int n = n0 + i, k = k0 + tx;
    if (n < N && k < K) out[(size_t)n * ldo + k] = tile[tx][i];
  }
}

// ---------------- h0 = bf16(concat(x, gene_emb)), pad cols zeroed ----------------
__global__ __launch_bounds__(256) void build_h0_k(
    const float* __restrict__ x, const float* __restrict__ gene, u16* __restrict__ h0)
{
  const int row = blockIdx.x;
  const float* s = (row < NDRUG) ? (x + (size_t)row * IND)
                                 : (gene + (size_t)(row - NDRUG) * IND);
  u16* d = h0 + (size_t)row * PIN;
  for (int i = threadIdx.x; i < PIN; i += 256) d[i] = (i < IND) ? f2bf(s[i]) : (u16)0;
}

// ---------------- per-(relation,dst) edge counts (clamped indices) ----------------
__global__ __launch_bounds__(256) void count_k(
    const int* __restrict__ dst, const int* __restrict__ et, int* __restrict__ cnt)
{
  int e = blockIdx.x * 256 + threadIdx.x;
  if (e < NE) {
    int r = iclamp(et[e], 0, NREL - 1);
    int d = iclamp(dst[e], 0, NT - 1);
    atomicAdd(&cnt[(size_t)r * NT + d], 1);
  }
}

// ---------------- dead-simple single-block exclusive scan ----------------
__global__ __launch_bounds__(256) void scan_simple_k(
    const int* __restrict__ in, int* __restrict__ out, int n)
{
  __shared__ int part[256];
  const int tid = threadIdx.x;
  const int chunk = (n + 255) / 256;
  const int lo = tid * chunk;
  const int hi = (lo + chunk < n) ? (lo + chunk) : n;
  int s = 0;
  for (int i = lo; i < hi; ++i) s += in[i];
  part[tid] = s;
  __syncthreads();
  if (tid == 0) {
    int run = 0;
    for (int i = 0; i < 256; ++i) { int t = part[i]; part[i] = run; run += t; }
  }
  __syncthreads();
  int run = part[tid];
  for (int i = lo; i < hi; ++i) { out[i] = run; run += in[i]; }
}

// ---------------- fill CSR edge source list (clamped) ----------------
__global__ __launch_bounds__(256) void fill_k(
    const int* __restrict__ src, const int* __restrict__ dst, const int* __restrict__ et,
    const int* __restrict__ offs, int* __restrict__ pos, int* __restrict__ esrc)
{
  int e = blockIdx.x * 256 + threadIdx.x;
  if (e < NE) {
    int r = iclamp(et[e], 0, NREL - 1);
    int d = iclamp(dst[e], 0, NT - 1);
    int b = r * NT + d;
    int p = offs[b] + atomicAdd(&pos[b], 1);
    p = iclamp(p, 0, NE - 1);
    esrc[p] = iclamp(src[e], 0, NT - 1);
  }
}

// ---------------- gather-mean for one relation (bf16 H -> bf16 out) ----------------
__global__ __launch_bounds__(256) void gather_k(
    const int* __restrict__ esrc, const int* __restrict__ offs, const int* __restrict__ cnt,
    int rel, const u16* __restrict__ H, int ldh, int nvec, u16* __restrict__ out, int ldo)
{
  const int i = blockIdx.x;
  const int b = rel * NT + i;
  int n = iclamp(cnt[b], 0, NE);
  int o = iclamp(offs[b], 0, NE - 1);
  if (o + n > NE) n = NE - o;
  u16* op = out + (size_t)i * ldo;
  if (n <= 0) {
    uint4 z = {0, 0, 0, 0};
    for (int v = threadIdx.x; v < nvec; v += 256) *(uint4*)(op + v * 8) = z;
    return;
  }
  const float inv = 1.0f / (float)n;
  for (int v = threadIdx.x; v < nvec; v += 256) {
    float acc[8] = {};
    for (int e = 0; e < n; ++e) {
      int si = iclamp(esrc[o + e], 0, NT - 1);
      const u16* hp = H + (size_t)si * ldh + v * 8;
      uint4 xv = *(const uint4*)hp;
      const u16* xu = (const u16*)&xv;
      #pragma unroll
      for (int j = 0; j < 8; ++j) acc[j] += bf2f(xu[j]);
    }
    u16 r[8];
    #pragma unroll
    for (int j = 0; j < 8; ++j) {
      float f = acc[j] * inv;
      f = (f == f) ? f : 0.0f;
      r[j] = f2bf(f);
    }
    *(uint4*)(op + v * 8) = *(uint4*)r;
  }
}

// ---------------- MFMA NT-GEMM, bf16 A/B; C dtype templated ----------------
// MODE 0: C = A.B + bias[col]          (init; CT=u16 bf16)
// MODE 1: C = C + A.B                  (accumulate RMW; CT=u16 bf16)
// MODE 2: C = relu(A.B + bias[col])    (final; CT=float, writes f32 emb)
template <int MODE, typename CT>
__global__ __launch_bounds__(256, 2) void gemm_nt(
    const u16* __restrict__ A, int lda,
    const u16* __restrict__ BT, int ldb,
    CT* __restrict__ C, int ldc,
    int M, int N, int K,
    const float* __restrict__ bias)
{
  constexpr int BM = 128, BN = 128, BK = 32, LDK = 40;  // +8 pad: 80B row stride
  __shared__ u16 As[BM * LDK];
  __shared__ u16 Bs[BN * LDK];
  const int tid = threadIdx.x;
  const int lane = tid & 63;
  const int wid = tid >> 6;
  const int wm = wid >> 1, wn = wid & 1;  // 2x2 wave grid, 64x64 per wave
  const int q = lane >> 4, l15 = lane & 15;
  const int m0 = blockIdx.y * BM, n0 = blockIdx.x * BN;
  const int sr = tid >> 1;
  const int sk = (tid & 1) * 16;

  f32x4 acc[4][4] = {};

  const int ktiles = (K + BK - 1) / BK;
  for (int kt = 0; kt < ktiles; ++kt) {
    const int k0 = kt * BK;
    // stage A [BM][BK]
    {
      const int gr = m0 + sr, gk = k0 + sk;
      u16 tmp[16] __attribute__((aligned(16)));
      if (gr < M && gk + 16 <= K) {
        const u16* Ap = A + (size_t)gr * lda + gk;
        *(uint4*)&tmp[0] = ((const uint4*)Ap)[0];
        *(uint4*)&tmp[8] = ((const uint4*)Ap)[1];
      } else {
        #pragma unroll
        for (int v = 0; v < 16; ++v) {
          int kk = gk + v;
          tmp[v] = (gr < M && kk < K) ? A[(size_t)gr * lda + kk] : (u16)0;
        }
      }
      *(uint4*)&As[sr * LDK + sk]     = *(uint4*)&tmp[0];
      *(uint4*)&As[sr * LDK + sk + 8] = *(uint4*)&tmp[8];
    }
    // stage B [BN][BK] from BT
    {
      const int gc = n0 + sr, gk = k0 + sk;
      u16 tmp[16] __attribute__((aligned(16)));
      if (gc < N && gk + 16 <= K) {
        const u16* Bp = BT + (size_t)gc * ldb + gk;
        *(uint4*)&tmp[0] = ((const uint4*)Bp)[0];
        *(uint4*)&tmp[8] = ((const uint4*)Bp)[1];
      } else {
        #pragma unroll
        for (int v = 0; v < 16; ++v) {
          int kk = gk + v;
          tmp[v] = (gc < N && kk < K) ? BT[(size_t)gc * ldb + kk] : (u16)0;
        }
      }
      *(uint4*)&Bs[sr * LDK + sk]     = *(uint4*)&tmp[0];
      *(uint4*)&Bs[sr * LDK + sk + 8] = *(uint4*)&tmp[8];
    }
    __syncthreads();

    bf16x8 af[4], bfr[4];
    #pragma unroll
    for (int i = 0; i < 4; ++i)
      af[i] = *(const bf16x8*)&As[(wm * 64 + i * 16 + l15) * LDK + q * 8];
    #pragma unroll
    for (int j = 0; j < 4; ++j)
      bfr[j] = *(const bf16x8*)&Bs[(wn * 64 + j * 16 + l15) * LDK + q * 8];
    #pragma unroll
    for (int i = 0; i < 4; ++i)
      #pragma unroll
      for (int j = 0; j < 4; ++j)
        acc[i][j] = __builtin_amdgcn_mfma_f32_16x16x32_bf16(af[i], bfr[j], acc[i][j], 0, 0, 0);
    __syncthreads();
  }

  // epilogue: C/D layout col=lane&15, row=quad*4+reg (m89/m91-verified)
  #pragma unroll
  for (int i = 0; i < 4; ++i) {
    #pragma unroll
    for (int t = 0; t < 4; ++t) {
      const int r = m0 + wm * 64 + i * 16 + q * 4 + t;
      if (r >= M) continue;
      #pragma unroll
      for (int j = 0; j < 4; ++j) {
        const int c = n0 + wn * 64 + j * 16 + l15;
        if (c < N) {
          const size_t idx = (size_t)r * ldc + c;
          float v = acc[i][j][t];
          v = (v == v) ? v : 0.0f;  // NaN scrub
          if (MODE == 0) {
            C[idx] = (CT)f2bf(v + bias[c]);
          } else if (MODE == 1) {
            float c0 = bf2f((u16)C[idx]);
            c0 = (c0 == c0) ? c0 : 0.0f;
            C[idx] = (CT)f2bf(c0 + v);
          } else {
            float s = v + bias[c];
            s = (s > 0.0f) ? s : 0.0f;
            ((float*)C)[idx] = s;  // f32 emb write
          }
        }
      }
    }
  }
}

// ---------------- in-place relu over bf16 [NT][pad], zeroing pads ----------------
__global__ __launch_bounds__(256) void relu_pad_k(u16* __restrict__ h, int real, int pad)
{
  const int r = blockIdx.x;
  u16* p = h + (size_t)r * pad;
  for (int c = threadIdx.x; c < pad; c += 256) {
    u16 x = p[c];
    p[c] = (c < real && bf2f(x) > 0.0f) ? x : (u16)0;
  }
}

// ---------------- lin2 + log_softmax: f32 emb -> f32 logits ----------------
__global__ __launch_bounds__(256) void head_k(
    const float* __restrict__ emb,
    const float* __restrict__ w, const float* __restrict__ b, float* __restrict__ out)
{
  const int row = blockIdx.x * 4 + (threadIdx.x >> 6);
  const int lane = threadIdx.x & 63;
  if (row >= NT) return;
  const float* e = emb + (size_t)row * D3;
  float s0 = 0.f, s1 = 0.f;
  for (int k = lane; k < D3; k += 64) {
    float v = e[k];
    s0 += v * w[2 * k];
    s1 += v * w[2 * k + 1];
  }
  #pragma unroll
  for (int off = 32; off > 0; off >>= 1) {
    s0 += __shfl_down(s0, off, 64);
    s1 += __shfl_down(s1, off, 64);
  }
  if (lane == 0) {
    s0 += b[0]; s1 += b[1];
    s0 = (s0 == s0) ? s0 : 0.0f;
    s1 = (s1 == s1) ? s1 : 0.0f;
    float m = fmaxf(s0, s1);
    float lse = m + logf(expf(s0 - m) + expf(s1 - m));
    out[2 * (size_t)row]     = s0 - lse;
    out[2 * (size_t)row + 1] = s1 - lse;
  }
}

extern "C" void kernel_launch(void* const* d_in, const int* in_sizes, int n_in,
                              void* d_out, int out_size, void* d_ws, size_t ws_size,
                              hipStream_t stream)
{
  (void)in_sizes; (void)n_in; (void)out_size;
  const float* x     = (const float*)d_in[0];
  const int*   ei    = (const int*)d_in[1];
  const int*   et    = (const int*)d_in[2];
  const float* gene  = (const float*)d_in[3];
  const float* W1    = (const float*)d_in[4];
  const float* root1 = (const float*)d_in[5];
  const float* b1    = (const float*)d_in[6];
  const float* W2    = (const float*)d_in[7];
  const float* root2 = (const float*)d_in[8];
  const float* b2    = (const float*)d_in[9];
  const float* l1w   = (const float*)d_in[10];
  const float* l1b   = (const float*)d_in[11];
  const float* l2w   = (const float*)d_in[12];
  const float* l2b   = (const float*)d_in[13];
  const int* srcI = ei;
  const int* dstI = ei + NE;

  char* base = (char*)d_ws;
  size_t off = 0;
  auto take = [&](size_t bytes) -> char* {
    char* p = base + off;
    off += (bytes + 255) & ~(size_t)255;
    return p;
  };
  u16* regA = (u16*)take((size_t)NT * PIN * 2);  // h0 bf16; later layer-2 C -> h2
  u16* regB = (u16*)take((size_t)NT * PIN * 2);  // agg bf16
  u16* regC = (u16*)take((size_t)NT * PD1 * 2);  // layer-1 C bf16 -> h1
  int* cnt  = (int*)take((size_t)NREL * NT * 4);
  int* pos  = (int*)take((size_t)NREL * NT * 4);
  int* offs = (int*)take((size_t)NREL * NT * 4);
  int* esrc = (int*)take((size_t)NE * 4);
  u16* BTr1 = (u16*)take((size_t)D1 * PIN * 2);
  u16* BTW1 = (u16*)take((size_t)NREL * D1 * PIN * 2);
  u16* BTr2 = (u16*)take((size_t)D2 * PD1 * 2);
  u16* BTW2 = (u16*)take((size_t)NREL * D2 * PD1 * 2);
  u16* BTl1 = (u16*)take((size_t)D3 * PD2 * 2);

  if (off > ws_size) return;  // signature: zero output -> absmax ~1.35

  float* outp = (float*)d_out;
  float* emb  = outp + (size_t)NT * 2;

  // ---- CSR build ----
  zero_i32_k<<<(NREL * NT + 255) / 256, 256, 0, stream>>>(cnt, NREL * NT);
  zero_i32_k<<<(NREL * NT + 255) / 256, 256, 0, stream>>>(pos, NREL * NT);
  count_k<<<(NE + 255) / 256, 256, 0, stream>>>(dstI, et, cnt);
  scan_simple_k<<<1, 256, 0, stream>>>(cnt, offs, NREL * NT);
  fill_k<<<(NE + 255) / 256, 256, 0, stream>>>(srcI, dstI, et, offs, pos, esrc);

  // ---- weight transposes (f32 -> bf16) ----
  dim3 tb(32, 8);
  transpose_k<<<dim3((D1 + 31) / 32, (IND + 31) / 32, 1),    tb, 0, stream>>>(root1, BTr1, IND, D1, PIN, 0, 0);
  transpose_k<<<dim3((D1 + 31) / 32, (IND + 31) / 32, NREL), tb, 0, stream>>>(W1, BTW1, IND, D1, PIN, (size_t)IND * D1, (size_t)D1 * PIN);
  transpose_k<<<dim3((D2 + 31) / 32, (D1 + 31) / 32, 1),     tb, 0, stream>>>(root2, BTr2, D1, D2, PD1, 0, 0);
  transpose_k<<<dim3((D2 + 31) / 32, (D1 + 31) / 32, NREL),  tb, 0, stream>>>(W2, BTW2, D1, D2, PD1, (size_t)D1 * D2, (size_t)D2 * PD1);
  transpose_k<<<dim3((D3 + 31) / 32, (D2 + 31) / 32, 1),     tb, 0, stream>>>(l1w, BTl1, D2, D3, PD2, 0, 0);

  build_h0_k<<<NT, 256, 0, stream>>>(x, gene, regA);

  // ---- layer 1: regC = h0@root1 + b1 + sum_r mean_r(h0)@W1_r ----
  dim3 g1((D1 + 127) / 128, (NT + 127) / 128);
  gemm_nt<0, u16><<<g1, 256, 0, stream>>>(regA, PIN, BTr1, PIN, regC, PD1, NT, D1, IND, b1);
  for (int r = 0; r < NREL; ++r) {
    gather_k<<<NT, 256, 0, stream>>>(esrc, offs, cnt, r, regA, PIN, PIN / 8, regB, PIN);
    gemm_nt<1, u16><<<g1, 256, 0, stream>>>(regB, PIN, BTW1 + (size_t)r * D1 * PIN, PIN, regC, PD1, NT, D1, IND, nullptr);
  }
  relu_pad_k<<<NT, 256, 0, stream>>>(regC, D1, PD1);  // regC = h1

  // ---- layer 2: regA = h1@root2 + b2 + sum_r mean_r(h1)@W2_r ----
  dim3 g2((D2 + 127) / 128, (NT + 127) / 128);
  gemm_nt<0, u16><<<g2, 256, 0, stream>>>(regC, PD1, BTr2, PD1, regA, PD2, NT, D2, D1, b2);
  for (int r = 0; r < NREL; ++r) {
    gather_k<<<NT, 256, 0, stream>>>(esrc, offs, cnt, r, regC, PD1, PD1 / 8, regB, PD1);
    gemm_nt<1, u16><<<g2, 256, 0, stream>>>(regB, PD1, BTW2 + (size_t)r * D2 * PD1, PD1, regA, PD2, NT, D2, D1, nullptr);
  }
  relu_pad_k<<<NT, 256, 0, stream>>>(regA, D2, PD2);  // regA = h2

  // ---- lin1 (fused bias+relu) -> f32 emb in d_out ----
  dim3 g3((D3 + 127) / 128, (NT + 127) / 128);
  gemm_nt<2, float><<<g3, 256, 0, stream>>>(regA, PD2, BTl1, PD2, emb, D3, NT, D3, D2, l1b);

  // ---- lin2 + log_softmax (f32) ----
  head_k<<<(NT + 3) / 4, 256, 0, stream>>>(emb, l2w, l2b, outp);
}